// Round 8
// baseline (4357.649 us; speedup 1.0000x reference)
//
#include <hip/hip_runtime.h>

#define T_STEPS 4096
#define BATCH   128
#define HID     256

typedef float f4 __attribute__((ext_vector_type(4)));

__device__ __forceinline__ float fast_tanh(float z) {
    // tanh(z) = 1 - 2/(exp(2z)+1); exact saturation, ~1e-6 abs err
    float e = __expf(2.0f * z);
    return 1.0f - 2.0f / (e + 1.0f);
}

__device__ __forceinline__ float rlane(float v, int l) {
    return __uint_as_float(__builtin_amdgcn_readlane(__float_as_uint(v), l));
}

// one level of the canonical GCN wave64 DPP reduction (VALU pipe)
template <int CTRL, int ROW_MASK>
__device__ __forceinline__ float dpp_add(float x) {
    int s = __builtin_amdgcn_update_dpp(0, __float_as_int(x), CTRL, ROW_MASK, 0xf, false);
    return x + __int_as_float(s);
}

#define RPT16(M) M(0) M(1) M(2) M(3) M(4) M(5) M(6) M(7) \
                 M(8) M(9) M(10) M(11) M(12) M(13) M(14) M(15)

// 1024 threads = 16 waves (4/SIMD, unified reg cap = 512/4 = 128/wave).
// Wave w owns k-slice [16w,16w+16); lane l owns columns 4l..4l+3.
// Round-7 fact: VALU cannot source AGPRs (asm rejected v_fma v,s,a,v) -> the
// only way to kill the per-fmac v_accvgpr_read is to keep weights in ARCH
// VGPRs. 64 weights + ~44 working = 108 <= 128 cap, so it fits; rounds 2-6
// the RA still evicted them to AGPRs because plain fmaf made eviction free.
// This round: hard "v" constraints at every use -> AGPR placement would cost
// 64 copies/step -> RA should keep the range in arch VGPRs.
__global__ __launch_bounds__(1024, 4)
void odenet_kernel(const float* __restrict__ x,
                   const float* __restrict__ W1, const float* __restrict__ b1,
                   const float* __restrict__ W2, const float* __restrict__ b2,
                   const float* __restrict__ W3, const float* __restrict__ b3,
                   float* __restrict__ out)
{
    const int b = blockIdx.x;    // batch element
    const int t = threadIdx.x;   // 0..1023
    const int w = t >> 6;        // wave 0..15: k-slice [16w,16w+16)
    const int l = t & 63;        // lane: columns 4l..4l+3
    const int k = 16 * w + (l & 15);   // this lane's h1 index (x4 redundant)

    __shared__ float x_lds[T_STEPS];       // 16 KB
    __shared__ float part[16][HID];        // 16 KB  part[w][j]
    __shared__ __align__(16) float red[4]; // per-combine-wave y-dot partials

    for (int i = t; i < T_STEPS; i += 1024) x_lds[i] = x[i * BATCH + b];

    // ---- W2 slice: rows 16w..16w+15, cols 4l..4l+3 (16 f4, coalesced) ----
    #define DECLQ(i) \
        f4 wq##i = *(const f4*)(W2 + (16*w + (i)) * HID + 4*l); \
        asm volatile("" : "+v"(wq##i));
    RPT16(DECLQ)

    // ---- layer-1 params for this lane's k ----
    const float w1a = W1[k];
    const float w1b = W1[HID + k];
    const float b1v = b1[k];

    // ---- combine params (threads 0..255, col j = t) ----
    const float b2v = (t < 256) ? b2[t] : 0.f;
    const float w3v = (t < 256) ? W3[t] : 0.f;
    const float b3v = b3[0];

    float y = 0.0f;
    __syncthreads();

    #pragma unroll 1
    for (int n = 0; n < T_STEPS; ++n) {
        if (t == 1023) out[n * BATCH + b] = y;   // emit y_n (pre-update)

        // ---- layer 1, in-wave (no barrier) ----
        const float xt = x_lds[n];
        const float h  = fast_tanh(fmaf(y, w1a, fmaf(xt, w1b, b1v)));

        // ---- GEMV: 16 SGPR broadcasts + 64 v_fma_f32 with "v" weights ----
        float a0 = 0.f, a1 = 0.f, a2 = 0.f, a3 = 0.f;
        #define STEPK(i) { \
            const float hs = rlane(h, i); \
            asm("v_fma_f32 %0, %8, %4, %0\n\t" \
                "v_fma_f32 %1, %8, %5, %1\n\t" \
                "v_fma_f32 %2, %8, %6, %2\n\t" \
                "v_fma_f32 %3, %8, %7, %3" \
                : "+v"(a0), "+v"(a1), "+v"(a2), "+v"(a3) \
                : "v"(wq##i.x), "v"(wq##i.y), "v"(wq##i.z), "v"(wq##i.w), \
                  "s"(hs)); }
        RPT16(STEPK)

        f4 acc; acc.x = a0; acc.y = a1; acc.z = a2; acc.w = a3;
        *(f4*)(&part[w][4 * l]) = acc;     // coalesced ds_write_b128
        __syncthreads();                   // B1: partials ready

        // ---- combine (threads 0..255): col sums, tanh, w3-dot, DPP reduce ----
        if (t < 256) {
            float s0 = 0.f, s1 = 0.f, s2 = 0.f, s3 = 0.f;
            #pragma unroll
            for (int p = 0; p < 4; ++p) {
                s0 += part[4*p + 0][t];
                s1 += part[4*p + 1][t];
                s2 += part[4*p + 2][t];
                s3 += part[4*p + 3][t];
            }
            float h2 = fast_tanh(((s0 + s1) + (s2 + s3)) + b2v);
            float p  = h2 * w3v;
            // canonical wave64 DPP reduce: total lands in lane 63
            p = dpp_add<0x111, 0xf>(p);   // row_shr:1
            p = dpp_add<0x112, 0xf>(p);   // row_shr:2
            p = dpp_add<0x114, 0xf>(p);   // row_shr:4
            p = dpp_add<0x118, 0xf>(p);   // row_shr:8
            p = dpp_add<0x142, 0xa>(p);   // row_bcast:15 (rows 1,3)
            p = dpp_add<0x143, 0xc>(p);   // row_bcast:31 (rows 2,3)
            if (l == 63) red[w] = p;      // combine waves w = 0..3
        }
        __syncthreads();                   // B2: red ready

        // all threads update y identically
        f4 r = *(const f4*)red;            // uniform ds_read_b128
        y += ((r.x + r.y) + (r.z + r.w)) + b3v;
    }
}

extern "C" void kernel_launch(void* const* d_in, const int* in_sizes, int n_in,
                              void* d_out, int out_size, void* d_ws, size_t ws_size,
                              hipStream_t stream) {
    const float* x  = (const float*)d_in[0];
    const float* W1 = (const float*)d_in[1];
    const float* b1 = (const float*)d_in[2];
    const float* W2 = (const float*)d_in[3];
    const float* b2 = (const float*)d_in[4];
    const float* W3 = (const float*)d_in[5];
    const float* b3 = (const float*)d_in[6];
    float* out = (float*)d_out;

    odenet_kernel<<<dim3(BATCH), dim3(1024), 0, stream>>>(x, W1, b1, W2, b2, W3, b3, out);
}

// Round 9
// 3491.169 us; speedup vs baseline: 1.2482x; 1.2482x over previous
//
#include <hip/hip_runtime.h>

#define T_STEPS 4096
#define BATCH   128
#define HID     256

typedef float f4 __attribute__((ext_vector_type(4)));

__device__ __forceinline__ float fast_tanh(float z) {
    // tanh(z) = 1 - 2/(exp(2z)+1); exact saturation, ~1e-6 abs err
    float e = __expf(2.0f * z);
    return 1.0f - 2.0f / (e + 1.0f);
}

__device__ __forceinline__ float rlane(float v, int l) {
    return __uint_as_float(__builtin_amdgcn_readlane(__float_as_uint(v), l));
}

// one level of the canonical GCN wave64 DPP reduction (VALU pipe)
template <int CTRL, int ROW_MASK>
__device__ __forceinline__ float dpp_add(float x) {
    int s = __builtin_amdgcn_update_dpp(0, __float_as_int(x), CTRL, ROW_MASK, 0xf, false);
    return x + __int_as_float(s);
}

#define RPT16(M) M(0) M(1) M(2) M(3) M(4) M(5) M(6) M(7) \
                 M(8) M(9) M(10) M(11) M(12) M(13) M(14) M(15)

// 1024 threads = 16 waves (4/SIMD, unified cap 128 regs/wave).
// Wave w owns k-slice [16w,16w+16); lane l owns columns 4l..4l+3.
// RA fact (rounds 4/6/8): hipcc homes big loop-invariant arrays in AGPRs
// regardless of slack; "v" constraints at USE sites just stream accvgpr_read
// copies (round 8: 4358us). This round: empty asm "+v" pin on every weight
// INSIDE the loop -> AGPR homing would cost 64 reads + 64 writes per step,
// arch-VGPR homing costs zero. 64 weights + ~44 working = 108 <= 128 budget.
__global__ __launch_bounds__(1024, 4)
void odenet_kernel(const float* __restrict__ x,
                   const float* __restrict__ W1, const float* __restrict__ b1,
                   const float* __restrict__ W2, const float* __restrict__ b2,
                   const float* __restrict__ W3, const float* __restrict__ b3,
                   float* __restrict__ out)
{
    const int b = blockIdx.x;    // batch element
    const int t = threadIdx.x;   // 0..1023
    const int w = t >> 6;        // wave 0..15: k-slice [16w,16w+16)
    const int l = t & 63;        // lane: columns 4l..4l+3
    const int k = 16 * w + (l & 15);   // this lane's h1 index (x4 redundant)

    __shared__ float x_lds[T_STEPS];       // 16 KB
    __shared__ float part[16][HID];        // 16 KB  part[w][j]
    __shared__ __align__(16) float red[4]; // per-combine-wave y-dot partials

    for (int i = t; i < T_STEPS; i += 1024) x_lds[i] = x[i * BATCH + b];

    // ---- W2 slice: rows 16w..16w+15, cols 4l..4l+3 (16 f4, coalesced) ----
    #define DECLQ(i) \
        f4 wq##i = *(const f4*)(W2 + (16*w + (i)) * HID + 4*l);
    RPT16(DECLQ)

    // ---- layer-1 params for this lane's k ----
    const float w1a = W1[k];
    const float w1b = W1[HID + k];
    const float b1v = b1[k];

    // ---- combine params (threads 0..255, col j = t) ----
    const float b2v = (t < 256) ? b2[t] : 0.f;
    const float w3v = (t < 256) ? W3[t] : 0.f;
    const float b3v = b3[0];

    float y = 0.0f;
    __syncthreads();

    #pragma unroll 1
    for (int n = 0; n < T_STEPS; ++n) {
        // ---- per-iteration arch-VGPR pin: makes AGPR homing cost 128
        //      copies/step, VGPR homing free (zero instructions) ----
        #define PINQ(i) asm volatile("" : "+v"(wq##i));
        RPT16(PINQ)

        if (t == 1023) out[n * BATCH + b] = y;   // emit y_n (pre-update)

        // ---- layer 1, in-wave (no barrier) ----
        const float xt = x_lds[n];
        const float h  = fast_tanh(fmaf(y, w1a, fmaf(xt, w1b, b1v)));

        // ---- GEMV: 16 readlane broadcasts + 64 fmac ----
        f4 acc = {0.f, 0.f, 0.f, 0.f};
        #define STEPK(i) { const float s = rlane(h, i); acc += s * wq##i; }
        RPT16(STEPK)
        *(f4*)(&part[w][4 * l]) = acc;     // coalesced ds_write_b128
        __syncthreads();                   // B1: partials ready

        // ---- combine (threads 0..255): col sums, tanh, w3-dot, DPP reduce ----
        if (t < 256) {
            float s0 = 0.f, s1 = 0.f, s2 = 0.f, s3 = 0.f;
            #pragma unroll
            for (int p = 0; p < 4; ++p) {
                s0 += part[4*p + 0][t];
                s1 += part[4*p + 1][t];
                s2 += part[4*p + 2][t];
                s3 += part[4*p + 3][t];
            }
            float h2 = fast_tanh(((s0 + s1) + (s2 + s3)) + b2v);
            float p  = h2 * w3v;
            // canonical wave64 DPP reduce: total lands in lane 63
            p = dpp_add<0x111, 0xf>(p);   // row_shr:1
            p = dpp_add<0x112, 0xf>(p);   // row_shr:2
            p = dpp_add<0x114, 0xf>(p);   // row_shr:4
            p = dpp_add<0x118, 0xf>(p);   // row_shr:8
            p = dpp_add<0x142, 0xa>(p);   // row_bcast:15 (rows 1,3)
            p = dpp_add<0x143, 0xc>(p);   // row_bcast:31 (rows 2,3)
            if (l == 63) red[w] = p;      // combine waves w = 0..3
        }
        __syncthreads();                   // B2: red ready

        // all threads update y identically
        f4 r = *(const f4*)red;            // uniform ds_read_b128
        y += ((r.x + r.y) + (r.z + r.w)) + b3v;
    }
}

extern "C" void kernel_launch(void* const* d_in, const int* in_sizes, int n_in,
                              void* d_out, int out_size, void* d_ws, size_t ws_size,
                              hipStream_t stream) {
    const float* x  = (const float*)d_in[0];
    const float* W1 = (const float*)d_in[1];
    const float* b1 = (const float*)d_in[2];
    const float* W2 = (const float*)d_in[3];
    const float* b2 = (const float*)d_in[4];
    const float* W3 = (const float*)d_in[5];
    const float* b3 = (const float*)d_in[6];
    float* out = (float*)d_out;

    odenet_kernel<<<dim3(BATCH), dim3(1024), 0, stream>>>(x, W1, b1, W2, b2, W3, b3, out);
}